// Round 1
// baseline (490.255 us; speedup 1.0000x reference)
//
#include <hip/hip_runtime.h>
#include <hip/hip_bf16.h>
#include <math.h>

#define D_MODEL 1024
#define H_NUM 16
#define HD 64
#define FF_DIM 2048
#define SEQ 2048
#define BATCH 4
#define M_TOK 8192  // BATCH*SEQ

typedef __attribute__((ext_vector_type(8))) short bf16x8;
typedef __attribute__((ext_vector_type(4))) float f32x4;

__device__ __forceinline__ short f2bf(float f) {
  __hip_bfloat16 h = __float2bfloat16(f);
  return *reinterpret_cast<short*>(&h);
}

__device__ __forceinline__ void gload16(const void* g, void* l) {
  __builtin_amdgcn_global_load_lds((const __attribute__((address_space(1))) void*)g,
                                   (__attribute__((address_space(3))) void*)l, 16, 0, 0);
}

// ---------------- weight transpose + cast: src fp32 [K][N] -> dst bf16 [N][K]
__global__ __launch_bounds__(256) void transpose_cast(const float* __restrict__ src,
                                                      short* __restrict__ dst,
                                                      int K, int N) {
  __shared__ float tile[64][65];
  const int n0 = blockIdx.x * 64, k0 = blockIdx.y * 64;
  const int tr = threadIdx.x >> 4;         // 0..15
  const int tc = (threadIdx.x & 15) * 4;   // 0..60
#pragma unroll
  for (int i = 0; i < 4; ++i) {
    int kr = tr + i * 16;
    float4 v = *(const float4*)(src + (size_t)(k0 + kr) * N + n0 + tc);
    tile[kr][tc] = v.x; tile[kr][tc + 1] = v.y; tile[kr][tc + 2] = v.z; tile[kr][tc + 3] = v.w;
  }
  __syncthreads();
#pragma unroll
  for (int i = 0; i < 4; ++i) {
    int r = tr + i * 16;
    short4 o;
    o.x = f2bf(tile[tc][r]);
    o.y = f2bf(tile[tc + 1][r]);
    o.z = f2bf(tile[tc + 2][r]);
    o.w = f2bf(tile[tc + 3][r]);
    *(short4*)(dst + (size_t)(n0 + r) * K + k0 + tc) = o;
  }
}

// ---------------- LayerNorm fp32 [rows][1024] -> bf16, one block per row
__global__ __launch_bounds__(256) void ln_bf16(const float* __restrict__ x,
                                               const float* __restrict__ g,
                                               const float* __restrict__ b,
                                               short* __restrict__ out) {
  const int row = blockIdx.x;
  const int t = threadIdx.x;
  const float* xr = x + (size_t)row * D_MODEL;
  float4 v = *(const float4*)(xr + t * 4);
  float s = v.x + v.y + v.z + v.w;
  float s2 = v.x * v.x + v.y * v.y + v.z * v.z + v.w * v.w;
#pragma unroll
  for (int m = 1; m < 64; m <<= 1) { s += __shfl_xor(s, m); s2 += __shfl_xor(s2, m); }
  __shared__ float ps[8];
  const int wid = t >> 6, lane = t & 63;
  if (lane == 0) { ps[wid] = s; ps[wid + 4] = s2; }
  __syncthreads();
  s = ps[0] + ps[1] + ps[2] + ps[3];
  s2 = ps[4] + ps[5] + ps[6] + ps[7];
  float mu = s * (1.f / D_MODEL);
  float rstd = rsqrtf(s2 * (1.f / D_MODEL) - mu * mu + 1e-5f);
  float4 gv = *(const float4*)(g + t * 4);
  float4 bv = *(const float4*)(b + t * 4);
  short4 o;
  o.x = f2bf((v.x - mu) * rstd * gv.x + bv.x);
  o.y = f2bf((v.y - mu) * rstd * gv.y + bv.y);
  o.z = f2bf((v.z - mu) * rstd * gv.z + bv.z);
  o.w = f2bf((v.w - mu) * rstd * gv.w + bv.w);
  *(short4*)(out + (size_t)row * D_MODEL + t * 4) = o;
}

// ---------------- 128x128 bf16 MFMA GEMM, BK=64, swizzled LDS, epilogue by MODE
// A [M][K] bf16 row-major; Bt [N][K] bf16 (B transposed). C = A*B.
// MODE 0: QKV scatter  (bias0/1/2 = bq/bk/bv, outb0/1/2 = q/k/v [BH][S][HD], q scaled)
// MODE 1: C + bias0 + resid -> outf (fp32)
// MODE 2: gelu(C + bias0) -> outb0 (bf16)
// MODE 3: C + bias0 + resid -> outf (fp32)   (resid may alias outf)
template <int MODE>
__global__ __launch_bounds__(256) void gemm128(const short* __restrict__ A,
                                               const short* __restrict__ Bt,
                                               const float* __restrict__ bias0,
                                               const float* __restrict__ bias1,
                                               const float* __restrict__ bias2,
                                               const float* resid, float* outf,
                                               short* outb0, short* outb1, short* outb2,
                                               int M, int N, int K) {
  __shared__ short As[128 * 64];
  __shared__ short Bs[128 * 64];
  const int tid = threadIdx.x;
  const int lane = tid & 63;
  const int wid = tid >> 6;
  const int wr = wid >> 1, wc = wid & 1;
  const int row0 = blockIdx.y * 128, col0 = blockIdx.x * 128;

  f32x4 acc[4][4];
#pragma unroll
  for (int i = 0; i < 4; ++i)
#pragma unroll
    for (int j = 0; j < 4; ++j) acc[i][j] = (f32x4){0.f, 0.f, 0.f, 0.f};

  const int str = tid >> 3;                  // staging row within 32-row group
  const int sch = (tid & 7) ^ (str & 7);     // pre-swizzled source chunk

  for (int k0 = 0; k0 < K; k0 += 64) {
#pragma unroll
    for (int c = 0; c < 4; ++c) {
      int r = c * 32 + str;
      gload16(A + (size_t)(row0 + r) * K + k0 + sch * 8, (char*)As + c * 4096 + tid * 16);
      gload16(Bt + (size_t)(col0 + r) * K + k0 + sch * 8, (char*)Bs + c * 4096 + tid * 16);
    }
    __syncthreads();
#pragma unroll
    for (int kk = 0; kk < 2; ++kk) {
      bf16x8 af[4], bfr[4];
#pragma unroll
      for (int mf = 0; mf < 4; ++mf) {
        int rr = wr * 64 + mf * 16 + (lane & 15);
        int ch = (kk * 4 + (lane >> 4)) ^ (rr & 7);
        af[mf] = *(const bf16x8*)((const char*)As + rr * 128 + ch * 16);
      }
#pragma unroll
      for (int nf = 0; nf < 4; ++nf) {
        int rr = wc * 64 + nf * 16 + (lane & 15);
        int ch = (kk * 4 + (lane >> 4)) ^ (rr & 7);
        bfr[nf] = *(const bf16x8*)((const char*)Bs + rr * 128 + ch * 16);
      }
#pragma unroll
      for (int mf = 0; mf < 4; ++mf)
#pragma unroll
        for (int nf = 0; nf < 4; ++nf)
          acc[mf][nf] = __builtin_amdgcn_mfma_f32_16x16x32_bf16(af[mf], bfr[nf], acc[mf][nf], 0, 0, 0);
    }
    __syncthreads();
  }

#pragma unroll
  for (int mf = 0; mf < 4; ++mf) {
#pragma unroll
    for (int nf = 0; nf < 4; ++nf) {
#pragma unroll
      for (int r = 0; r < 4; ++r) {
        const int row = row0 + wr * 64 + mf * 16 + ((lane >> 4) << 2) + r;
        const int col = col0 + wc * 64 + nf * 16 + (lane & 15);
        float val = acc[mf][nf][r];
        if (MODE == 0) {
          const int which = col >> 10, nn = col & 1023;
          val += (which == 0 ? bias0[nn] : which == 1 ? bias1[nn] : bias2[nn]);
          if (which == 0) val *= 0.125f;  // fold softmax scale 1/sqrt(64) into q
          const int bb = row >> 11, s = row & 2047;
          const size_t dst = (((size_t)((bb << 4) + (nn >> 6)) << 11) + s) * HD + (nn & 63);
          short* o = (which == 0 ? outb0 : which == 1 ? outb1 : outb2);
          o[dst] = f2bf(val);
        } else if (MODE == 2) {
          val += bias0[col];
          float gl = 0.5f * val * (1.f + erff(val * 0.70710678118f));
          outb0[(size_t)row * N + col] = f2bf(gl);
        } else {  // MODE 1 and 3
          val += bias0[col] + resid[(size_t)row * N + col];
          outf[(size_t)row * N + col] = val;
        }
      }
    }
  }
}

// ---------------- flash attention: grid (qtiles=32, bh=64), 256 threads
// q,k,v bf16 [BH][SEQ][HD] (q pre-scaled). ctx bf16 [B][SEQ][D] token-major.
__global__ __launch_bounds__(256) void attn64(const short* __restrict__ q,
                                              const short* __restrict__ k,
                                              const short* __restrict__ v,
                                              short* __restrict__ ctx) {
  __shared__ short Ks[64 * 64];
  __shared__ short Vt[64 * 64];
  __shared__ short Ps[64 * 64];
  const int tid = threadIdx.x;
  const int lane = tid & 63;
  const int wid = tid >> 6;
  const int qt = blockIdx.x, bh = blockIdx.y;
  const size_t base = (size_t)bh * SEQ * HD;

  // Q fragments for this wave's 16 rows (kept in registers)
  bf16x8 aq[2];
#pragma unroll
  for (int kk = 0; kk < 2; ++kk)
    aq[kk] = *(const bf16x8*)(q + base + (size_t)(qt * 64 + wid * 16 + (lane & 15)) * HD +
                              kk * 32 + (lane >> 4) * 8);

  float mreg[4], lreg[4];
  f32x4 oc[4];
#pragma unroll
  for (int r = 0; r < 4; ++r) { mreg[r] = -1e30f; lreg[r] = 0.f; }
#pragma unroll
  for (int c = 0; c < 4; ++c) oc[c] = (f32x4){0.f, 0.f, 0.f, 0.f};

  const int str = tid >> 3;
  const int sch = (tid & 7) ^ (str & 7);
  const int vkey = tid & 63, vhb = (tid >> 6) * 16;

  for (int kt = 0; kt < 32; ++kt) {
    const short* kb = k + base + (size_t)kt * 64 * HD;
    const short* vb = v + base + (size_t)kt * 64 * HD;
    // stage K tile [64][64] via global_load_lds, pre-swizzled source
#pragma unroll
    for (int c = 0; c < 2; ++c) {
      int r = c * 32 + str;
      gload16(kb + (size_t)r * HD + sch * 8, (char*)Ks + c * 4096 + tid * 16);
    }
    // stage V transposed: Vt[hd][key], swizzled writes (2 lanes/bank)
    {
      bf16x8 v0 = *(const bf16x8*)(vb + (size_t)vkey * HD + vhb);
      bf16x8 v1 = *(const bf16x8*)(vb + (size_t)vkey * HD + vhb + 8);
#pragma unroll
      for (int i = 0; i < 8; ++i) {
        int hd0 = vhb + i;
        *(short*)((char*)Vt + ((hd0 * 128 + vkey * 2) ^ ((hd0 & 7) << 4))) = v0[i];
        int hd1 = vhb + 8 + i;
        *(short*)((char*)Vt + ((hd1 * 128 + vkey * 2) ^ ((hd1 & 7) << 4))) = v1[i];
      }
    }
    __syncthreads();

    // S = Q K^T  (rows: this wave's 16 q-rows; cols: 64 keys in 4 frags)
    f32x4 sf[4];
#pragma unroll
    for (int c = 0; c < 4; ++c) {
      sf[c] = (f32x4){0.f, 0.f, 0.f, 0.f};
#pragma unroll
      for (int kk = 0; kk < 2; ++kk) {
        int rr = c * 16 + (lane & 15);
        int ch = (kk * 4 + (lane >> 4)) ^ (rr & 7);
        bf16x8 bk = *(const bf16x8*)((const char*)Ks + rr * 128 + ch * 16);
        sf[c] = __builtin_amdgcn_mfma_f32_16x16x32_bf16(aq[kk], bk, sf[c], 0, 0, 0);
      }
    }

    // online softmax: row max over 4 frags then 16-lane group reduce
    float mx[4];
#pragma unroll
    for (int r = 0; r < 4; ++r)
      mx[r] = fmaxf(fmaxf(sf[0][r], sf[1][r]), fmaxf(sf[2][r], sf[3][r]));
#pragma unroll
    for (int m = 1; m < 16; m <<= 1)
#pragma unroll
      for (int r = 0; r < 4; ++r) mx[r] = fmaxf(mx[r], __shfl_xor(mx[r], m));
    float alpha[4], rs[4];
#pragma unroll
    for (int r = 0; r < 4; ++r) {
      float mn = fmaxf(mreg[r], mx[r]);
      alpha[r] = __expf(mreg[r] - mn);
      mreg[r] = mn;
      rs[r] = 0.f;
    }
#pragma unroll
    for (int c = 0; c < 4; ++c)
#pragma unroll
      for (int r = 0; r < 4; ++r) {
        float p = __expf(sf[c][r] - mreg[r]);
        sf[c][r] = p;
        rs[r] += p;
      }
#pragma unroll
    for (int m = 1; m < 16; m <<= 1)
#pragma unroll
      for (int r = 0; r < 4; ++r) rs[r] += __shfl_xor(rs[r], m);
#pragma unroll
    for (int r = 0; r < 4; ++r) lreg[r] = lreg[r] * alpha[r] + rs[r];
#pragma unroll
    for (int c = 0; c < 4; ++c)
#pragma unroll
      for (int r = 0; r < 4; ++r) oc[c][r] *= alpha[r];

    // write P (bf16) to own-wave rows of Ps, swizzled; no barrier needed
#pragma unroll
    for (int c = 0; c < 4; ++c)
#pragma unroll
      for (int r = 0; r < 4; ++r) {
        int prow = wid * 16 + ((lane >> 4) << 2) + r;
        int off = (prow * 128 + (c * 16 + (lane & 15)) * 2) ^ ((prow & 7) << 4);
        *(short*)((char*)Ps + off) = f2bf(sf[c][r]);
      }

    // ctx += P V
    bf16x8 ap[2];
#pragma unroll
    for (int ks = 0; ks < 2; ++ks) {
      int prow = wid * 16 + (lane & 15);
      int ch = (ks * 4 + (lane >> 4)) ^ (prow & 7);
      ap[ks] = *(const bf16x8*)((const char*)Ps + prow * 128 + ch * 16);
    }
#pragma unroll
    for (int c = 0; c < 4; ++c)
#pragma unroll
      for (int ks = 0; ks < 2; ++ks) {
        int vr = c * 16 + (lane & 15);
        int ch = (ks * 4 + (lane >> 4)) ^ (vr & 7);
        bf16x8 bv = *(const bf16x8*)((const char*)Vt + vr * 128 + ch * 16);
        oc[c] = __builtin_amdgcn_mfma_f32_16x16x32_bf16(ap[ks], bv, oc[c], 0, 0, 0);
      }
    __syncthreads();
  }

  // normalize and write ctx in [B][S][D] token-major layout
  const int b = bh >> 4, hh = bh & 15;
#pragma unroll
  for (int c = 0; c < 4; ++c)
#pragma unroll
    for (int r = 0; r < 4; ++r) {
      int s = qt * 64 + wid * 16 + ((lane >> 4) << 2) + r;
      size_t off = ((size_t)(b * SEQ + s)) * D_MODEL + hh * HD + c * 16 + (lane & 15);
      ctx[off] = f2bf(oc[c][r] / lreg[r]);
    }
}

// ---------------- launcher
extern "C" void kernel_launch(void* const* d_in, const int* in_sizes, int n_in,
                              void* d_out, int out_size, void* d_ws, size_t ws_size,
                              hipStream_t stream) {
  const float* x  = (const float*)d_in[0];
  const float* Wq = (const float*)d_in[1];
  const float* bq = (const float*)d_in[2];
  const float* Wk = (const float*)d_in[3];
  const float* bk = (const float*)d_in[4];
  const float* Wv = (const float*)d_in[5];
  const float* bv = (const float*)d_in[6];
  const float* Wo = (const float*)d_in[7];
  const float* bo = (const float*)d_in[8];
  const float* g1 = (const float*)d_in[9];
  const float* b1 = (const float*)d_in[10];
  const float* g2 = (const float*)d_in[11];
  const float* b2 = (const float*)d_in[12];
  const float* W1 = (const float*)d_in[13];
  const float* bf1 = (const float*)d_in[14];
  const float* W2 = (const float*)d_in[15];
  const float* bf2 = (const float*)d_in[16];

  char* w = (char*)d_ws;
  short* WqkvT = (short*)w; w += (size_t)3072 * 1024 * 2;      // 6 MB
  short* WoT   = (short*)w; w += (size_t)1024 * 1024 * 2;      // 2 MB
  short* W1T   = (short*)w; w += (size_t)2048 * 1024 * 2;      // 4 MB
  short* W2T   = (short*)w; w += (size_t)1024 * 2048 * 2;      // 4 MB
  short* xn    = (short*)w; w += (size_t)M_TOK * 1024 * 2;     // 16 MB
  short* qb    = (short*)w; w += (size_t)M_TOK * 1024 * 2;
  short* kb    = (short*)w; w += (size_t)M_TOK * 1024 * 2;
  short* vb    = (short*)w; w += (size_t)M_TOK * 1024 * 2;
  short* ctxb  = (short*)w; w += (size_t)M_TOK * 1024 * 2;
  short* xn2   = (short*)w; w += (size_t)M_TOK * 1024 * 2;
  short* hb    = (short*)w; w += (size_t)M_TOK * 2048 * 2;     // 32 MB

  dim3 blk(256);

  // weights -> bf16 transposed
  transpose_cast<<<dim3(16, 16), blk, 0, stream>>>(Wq, WqkvT, 1024, 1024);
  transpose_cast<<<dim3(16, 16), blk, 0, stream>>>(Wk, WqkvT + 1024 * 1024, 1024, 1024);
  transpose_cast<<<dim3(16, 16), blk, 0, stream>>>(Wv, WqkvT + 2 * 1024 * 1024, 1024, 1024);
  transpose_cast<<<dim3(16, 16), blk, 0, stream>>>(Wo, WoT, 1024, 1024);
  transpose_cast<<<dim3(32, 16), blk, 0, stream>>>(W1, W1T, 1024, 2048);
  transpose_cast<<<dim3(16, 32), blk, 0, stream>>>(W2, W2T, 2048, 1024);

  // LN1
  ln_bf16<<<M_TOK, blk, 0, stream>>>(x, g1, b1, xn);

  // QKV projection (fused 3072-wide GEMM, scatter to q/k/v head layout)
  gemm128<0><<<dim3(24, 64), blk, 0, stream>>>(xn, WqkvT, bq, bk, bv,
                                               nullptr, nullptr, qb, kb, vb,
                                               M_TOK, 3072, 1024);

  // attention
  attn64<<<dim3(32, 64), blk, 0, stream>>>(qb, kb, vb, ctxb);

  // out proj + residual -> d_out (fp32 x2)
  gemm128<1><<<dim3(8, 64), blk, 0, stream>>>(ctxb, WoT, bo, nullptr, nullptr,
                                              x, (float*)d_out, nullptr, nullptr, nullptr,
                                              M_TOK, 1024, 1024);

  // LN2 on x2
  ln_bf16<<<M_TOK, blk, 0, stream>>>((const float*)d_out, g2, b2, xn2);

  // FFN1 + GELU
  gemm128<2><<<dim3(16, 64), blk, 0, stream>>>(xn2, W1T, bf1, nullptr, nullptr,
                                               nullptr, nullptr, hb, nullptr, nullptr,
                                               M_TOK, 2048, 1024);

  // FFN2 + residual (in-place on d_out)
  gemm128<3><<<dim3(8, 64), blk, 0, stream>>>(hb, W2T, bf2, nullptr, nullptr,
                                              (const float*)d_out, (float*)d_out,
                                              nullptr, nullptr, nullptr,
                                              M_TOK, 1024, 2048);
}